// Round 11
// baseline (2444.442 us; speedup 1.0000x reference)
//
#include <hip/hip_runtime.h>
#include <hip/hip_bf16.h>
#include <hip/hip_cooperative_groups.h>
#include <stdint.h>

namespace cg = cooperative_groups;

typedef uint16_t u16;
typedef __attribute__((ext_vector_type(8))) __bf16 bf16x8;
typedef __attribute__((ext_vector_type(4))) float f32x4;
typedef __attribute__((ext_vector_type(4))) u16 u16x4;

// Problem constants
#define BSZ   256
#define NN    512
#define TT    12
#define FF    12
#define HID   1536
#define INSZ  6144    // N*F = LSTM input size
#define GATES 6144    // 4*HID
#define MROWS 3072    // FF*BSZ rows of the hoisted input GEMM
#define SPLITK 2
#define KSPL  (HID / SPLITK)   // 768

static __device__ __forceinline__ u16 f2bf(float x) {
  uint32_t u = __builtin_bit_cast(uint32_t, x);
  u += 0x7fffu + ((u >> 16) & 1u);   // RNE
  return (u16)(u >> 16);
}

static __device__ __forceinline__ float sigm(float x) {
  return 1.0f / (1.0f + expf(-x));
}

// ---------------- fp32 -> bf16 convert (4 elems/thread, grid-stride) ----------------
__global__ void cvt_bf16(const float* __restrict__ in, u16* __restrict__ out, long n4) {
  long stride = (long)gridDim.x * blockDim.x;
  for (long i = (long)blockIdx.x * blockDim.x + threadIdx.x; i < n4; i += stride) {
    float4 v = ((const float4*)in)[i];
    u16x4 r = { f2bf(v.x), f2bf(v.y), f2bf(v.z), f2bf(v.w) };
    ((u16x4*)out)[i] = r;
  }
}

// ---------------- pack X: 4 k's per thread -> coalesced u16x4 writes ----------------
__global__ void pack_x4(const float* __restrict__ X, u16* __restrict__ Ax) {
  int idx = blockIdx.x * blockDim.x + threadIdx.x;   // (b, k4), k4 in [0,1536)
  int b  = idx / (INSZ / 4);
  int k4 = idx - b * (INSZ / 4);
  const float* xp = X + (size_t)b * (INSZ * FF) + (size_t)k4 * (4 * FF);
  float4 v[12];   // 48 floats = [kk 0..3][f 0..11]
#pragma unroll
  for (int j = 0; j < 12; ++j) v[j] = ((const float4*)xp)[j];
  const float* vf = (const float*)v;
#pragma unroll
  for (int f = 0; f < FF; ++f) {
    u16x4 w = { f2bf(vf[0 * FF + f]), f2bf(vf[1 * FF + f]),
                f2bf(vf[2 * FF + f]), f2bf(vf[3 * FF + f]) };
    *(u16x4*)&Ax[(size_t)(f * BSZ + b) * INSZ + k4 * 4] = w;
  }
}

// =====================================================================
// Deep-pipelined bf16 GEMM (R8 version, known-good 212 us)
// =====================================================================
#define BM8 192
#define BN8 384
#define LDSA_SZ 24576
#define LDSB_SZ 49152
#define LDS_TOTAL (2 * (LDSA_SZ + LDSB_SZ))   // 147456

#define GLL(src, dst)                                                          \
  __builtin_amdgcn_global_load_lds(                                            \
      (const __attribute__((address_space(1))) void*)(src),                    \
      (__attribute__((address_space(3))) void*)(dst), 16, 0, 0)

#define SBAR() asm volatile("s_barrier" ::: "memory")
#define SCHED_FENCE_DS() __builtin_amdgcn_sched_barrier(0x7F)
#define WAIT_LGKM0()                                                           \
  do {                                                                         \
    asm volatile("s_waitcnt lgkmcnt(0)" ::: "memory");                         \
    __builtin_amdgcn_sched_barrier(0);                                         \
  } while (0)

__global__ __launch_bounds__(512, 1) void gemm8p(
    const u16* __restrict__ A, const u16* __restrict__ Bt,
    const float* __restrict__ bi, const float* __restrict__ bh,
    float* __restrict__ C, int M, int N, int K) {
  extern __shared__ __align__(16) char lds[];
  const int tid  = threadIdx.x;
  const int lane = tid & 63;
  const int wid  = tid >> 6;
  const int wr   = wid >> 2;
  const int wc   = wid & 3;

  const int nbx  = N / BN8;
  const int cpx  = gridDim.x >> 3;
  const int orig = blockIdx.x;
  const int wgid = (orig & 7) * cpx + (orig >> 3);
  const int m0   = (wgid / nbx) * BM8;
  const int n0   = (wgid % nbx) * BN8;

  const int fr    = lane & 15;
  const int kb    = (lane >> 4) << 4;
  const int swz   = (fr & 7) << 4;
  const int colp0 = kb ^ swz;
  const int colp1 = (64 | kb) ^ swz;

  const int srow = tid >> 3;
  const int scb  = ((tid & 7) << 4) ^ ((srow & 7) << 4);
  const u16* gA = A  + (size_t)(m0 + srow) * K + (scb >> 1);
  const u16* gB = Bt + (size_t)(n0 + srow) * K + (scb >> 1);
  const int wdst = wid << 10;

  char* ldsA = lds;
  char* ldsB = lds + 2 * LDSA_SZ;
  char* aRowB = ldsA + (wr * 96 + fr) * 128;
  char* bRowB = ldsB + (wc * 96 + fr) * 128;

  f32x4 acc[6][6] = {};
  const int NT = K >> 6;

#pragma unroll
  for (int c = 0; c < 3; ++c) GLL(gA + (size_t)c * 64 * K, ldsA + c * 8192 + wdst);
#pragma unroll
  for (int c = 0; c < 6; ++c) GLL(gB + (size_t)c * 64 * K, ldsB + c * 8192 + wdst);

  for (int t = 0; t < NT; ++t) {
    const int p = t & 1;
    char* aRow = aRowB + p * LDSA_SZ;
    char* bRow = bRowB + p * LDSB_SZ;
    char* An = ldsA + (p ^ 1) * LDSA_SZ;
    char* Bn = ldsB + (p ^ 1) * LDSB_SZ;
    const u16* gAn = gA + (size_t)(t + 1) * 64;
    const u16* gBn = gB + (size_t)(t + 1) * 64;
    const bool pf = (t + 1 < NT);

    bf16x8 a0[2][3], a1[2][3], b0[2][3], b1[2][3];

    if (pf) {
#pragma unroll
      for (int c = 0; c < 3; ++c) GLL(gAn + (size_t)c * 64 * K, An + c * 8192 + wdst);
      asm volatile("s_waitcnt vmcnt(3)" ::: "memory");
    } else {
      asm volatile("s_waitcnt vmcnt(0)" ::: "memory");
    }
    SBAR();

#pragma unroll
    for (int i = 0; i < 3; ++i) {
      a0[0][i] = *(const bf16x8*)(aRow + i * 2048 + colp0);
      a0[1][i] = *(const bf16x8*)(aRow + i * 2048 + colp1);
      b0[0][i] = *(const bf16x8*)(bRow + i * 2048 + colp0);
      b0[1][i] = *(const bf16x8*)(bRow + i * 2048 + colp1);
    }
    __builtin_amdgcn_s_setprio(1);
#pragma unroll
    for (int i = 0; i < 3; ++i)
#pragma unroll
      for (int j = 0; j < 3; ++j) {
        acc[i][j] = __builtin_amdgcn_mfma_f32_16x16x32_bf16(a0[0][i], b0[0][j], acc[i][j], 0, 0, 0);
        acc[i][j] = __builtin_amdgcn_mfma_f32_16x16x32_bf16(a0[1][i], b0[1][j], acc[i][j], 0, 0, 0);
      }
    __builtin_amdgcn_s_setprio(0);
    if (pf) {
      GLL(gBn + (size_t)0 * 64 * K, Bn + 0 * 8192 + wdst);
      GLL(gBn + (size_t)1 * 64 * K, Bn + 1 * 8192 + wdst);
    }
    SCHED_FENCE_DS();

#pragma unroll
    for (int i = 0; i < 3; ++i) {
      b1[0][i] = *(const bf16x8*)(bRow + (3 + i) * 2048 + colp0);
      b1[1][i] = *(const bf16x8*)(bRow + (3 + i) * 2048 + colp1);
    }
    __builtin_amdgcn_s_setprio(1);
#pragma unroll
    for (int i = 0; i < 3; ++i)
#pragma unroll
      for (int j = 0; j < 3; ++j) {
        acc[i][3 + j] = __builtin_amdgcn_mfma_f32_16x16x32_bf16(a0[0][i], b1[0][j], acc[i][3 + j], 0, 0, 0);
        acc[i][3 + j] = __builtin_amdgcn_mfma_f32_16x16x32_bf16(a0[1][i], b1[1][j], acc[i][3 + j], 0, 0, 0);
      }
    __builtin_amdgcn_s_setprio(0);
    if (pf) {
      GLL(gBn + (size_t)2 * 64 * K, Bn + 2 * 8192 + wdst);
      GLL(gBn + (size_t)3 * 64 * K, Bn + 3 * 8192 + wdst);
    }
    SCHED_FENCE_DS();

#pragma unroll
    for (int i = 0; i < 3; ++i) {
      a1[0][i] = *(const bf16x8*)(aRow + (3 + i) * 2048 + colp0);
      a1[1][i] = *(const bf16x8*)(aRow + (3 + i) * 2048 + colp1);
    }
    __builtin_amdgcn_s_setprio(1);
#pragma unroll
    for (int i = 0; i < 3; ++i)
#pragma unroll
      for (int j = 0; j < 3; ++j) {
        acc[3 + i][3 + j] = __builtin_amdgcn_mfma_f32_16x16x32_bf16(a1[0][i], b1[0][j], acc[3 + i][3 + j], 0, 0, 0);
        acc[3 + i][3 + j] = __builtin_amdgcn_mfma_f32_16x16x32_bf16(a1[1][i], b1[1][j], acc[3 + i][3 + j], 0, 0, 0);
      }
    __builtin_amdgcn_s_setprio(0);
    if (pf) {
      GLL(gBn + (size_t)4 * 64 * K, Bn + 4 * 8192 + wdst);
      GLL(gBn + (size_t)5 * 64 * K, Bn + 5 * 8192 + wdst);
    }
    SCHED_FENCE_DS();

    __builtin_amdgcn_s_setprio(1);
#pragma unroll
    for (int i = 0; i < 3; ++i)
#pragma unroll
      for (int j = 0; j < 3; ++j) {
        acc[3 + i][j] = __builtin_amdgcn_mfma_f32_16x16x32_bf16(a1[0][i], b0[0][j], acc[3 + i][j], 0, 0, 0);
        acc[3 + i][j] = __builtin_amdgcn_mfma_f32_16x16x32_bf16(a1[1][i], b0[1][j], acc[3 + i][j], 0, 0, 0);
      }
    __builtin_amdgcn_s_setprio(0);

    SBAR();
  }

  const int r0 = (lane >> 4) << 2;
  const int cc = lane & 15;
#pragma unroll
  for (int j = 0; j < 6; ++j) {
    const int col = n0 + wc * 96 + j * 16 + cc;
    const float bv = bi[col] + bh[col];
#pragma unroll
    for (int i = 0; i < 6; ++i) {
      const size_t rbase = (size_t)(m0 + wr * 96 + i * 16 + r0) * N + col;
#pragma unroll
      for (int r = 0; r < 4; ++r)
        C[rbase + (size_t)r * N] = acc[i][j][r] + bv;
    }
  }
}

// ---------------- gemm-phase body (shared by persistent + fallback) ----------------
static __device__ __forceinline__ void step_gemm_body(
    const u16* __restrict__ gA, const u16* __restrict__ gB, int K,
    char* ldsA, char* ldsB, char* aRowB, char* bRowB, int wdst,
    int colp0, int colp1, f32x4 acc[2][2]) {
  const int NT = KSPL >> 6;   // 12

  GLL(gA,                  ldsA + wdst);
  GLL(gA + (size_t)32 * K, ldsA + 4096 + wdst);
  GLL(gB,                  ldsB + wdst);
  GLL(gB + (size_t)32 * K, ldsB + 4096 + wdst);

  for (int t = 0; t < NT; ++t) {
    const int p = t & 1;
    char* aRow = aRowB + p * 8192;
    char* bRow = bRowB + p * 8192;
    char* An = ldsA + (p ^ 1) * 8192;
    char* Bn = ldsB + (p ^ 1) * 8192;
    const u16* gAn = gA + (size_t)(t + 1) * 64;
    const u16* gBn = gB + (size_t)(t + 1) * 64;

    if (t + 1 < NT) {
      GLL(gAn,                  An + wdst);
      GLL(gAn + (size_t)32 * K, An + 4096 + wdst);
      GLL(gBn,                  Bn + wdst);
      GLL(gBn + (size_t)32 * K, Bn + 4096 + wdst);
      asm volatile("s_waitcnt vmcnt(4)" ::: "memory");
    } else {
      asm volatile("s_waitcnt vmcnt(0)" ::: "memory");
    }
    SBAR();

    bf16x8 a[2][2], b[2][2];
#pragma unroll
    for (int i = 0; i < 2; ++i) {
      a[0][i] = *(const bf16x8*)(aRow + i * 2048 + colp0);
      a[1][i] = *(const bf16x8*)(aRow + i * 2048 + colp1);
      b[0][i] = *(const bf16x8*)(bRow + i * 2048 + colp0);
      b[1][i] = *(const bf16x8*)(bRow + i * 2048 + colp1);
    }
    WAIT_LGKM0();
    __builtin_amdgcn_s_setprio(1);
#pragma unroll
    for (int i = 0; i < 2; ++i)
#pragma unroll
      for (int j = 0; j < 2; ++j) {
        acc[i][j] = __builtin_amdgcn_mfma_f32_16x16x32_bf16(a[0][i], b[0][j], acc[i][j], 0, 0, 0);
        acc[i][j] = __builtin_amdgcn_mfma_f32_16x16x32_bf16(a[1][i], b[1][j], acc[i][j], 0, 0, 0);
      }
    __builtin_amdgcn_s_setprio(0);
    SBAR();
  }
}

// ---------------- cell item (device helper) ----------------
static __device__ __forceinline__ void cell_item(
    int idx, const float* __restrict__ XW_f, const float* __restrict__ HWb,
    float* __restrict__ c, u16* __restrict__ h_bf, float* __restrict__ hs_f,
    int first) {
  int b = idx / (HID / 4);
  int q = idx - b * (HID / 4);
  size_t rowq = (size_t)b * (GATES / 4);

  const float4* xw = (const float4*)XW_f;
  float4 gi = xw[rowq + q];
  float4 gf = xw[rowq + 384 + q];
  float4 gg = xw[rowq + 768 + q];
  float4 go = xw[rowq + 1152 + q];
  float4 cp = {0.f, 0.f, 0.f, 0.f};
  if (!first) {
#pragma unroll
    for (int s = 0; s < SPLITK; ++s) {
      const float4* hg = (const float4*)(HWb + (size_t)s * BSZ * GATES);
      float4 u;
      u = hg[rowq + q];
      gi.x += u.x; gi.y += u.y; gi.z += u.z; gi.w += u.w;
      u = hg[rowq + 384 + q];
      gf.x += u.x; gf.y += u.y; gf.z += u.z; gf.w += u.w;
      u = hg[rowq + 768 + q];
      gg.x += u.x; gg.y += u.y; gg.z += u.z; gg.w += u.w;
      u = hg[rowq + 1152 + q];
      go.x += u.x; go.y += u.y; go.z += u.z; go.w += u.w;
    }
    cp = ((const float4*)c)[idx];
  }
  float4 cn, h;
  {
    float* pi = (float*)&gi; float* pf_ = (float*)&gf; float* pg = (float*)&gg;
    float* po = (float*)&go; float* pc = (float*)&cp;
    float* pcn = (float*)&cn; float* ph = (float*)&h;
#pragma unroll
    for (int e = 0; e < 4; ++e) {
      float cv = sigm(pf_[e]) * pc[e] + sigm(pi[e]) * tanhf(pg[e]);
      pcn[e] = cv;
      ph[e]  = tanhf(sigm(po[e]) * tanhf(cv));
    }
  }
  ((float4*)c)[idx] = cn;
  ((float4*)hs_f)[idx] = h;
  u16x4 hb = { f2bf(h.x), f2bf(h.y), f2bf(h.z), f2bf(h.w) };
  ((u16x4*)h_bf)[idx] = hb;
}

// =====================================================================
// Persistent cooperative LSTM recurrence (launch_bounds(256,4) ->
// VGPR<=128, occupancy 4 blocks/CU, coop grid budget 1024 >= 768).
// =====================================================================
__global__ __launch_bounds__(256, 4) void lstm_persist(
    const u16* __restrict__ Whhb,
    const float* __restrict__ XW,
    float* __restrict__ HW,
    u16* __restrict__ hbf,
    float* __restrict__ cbuf,
    float* __restrict__ hs) {
  cg::grid_group grid = cg::this_grid();
  __shared__ __align__(16) char lds[32768];

  const int tid  = threadIdx.x;
  const int bid  = blockIdx.x;
  const int lane = tid & 63;
  const int wid  = tid >> 6;
  const int wr   = wid >> 1;
  const int wc   = wid & 1;
  const int n0   = (bid % 96) * 64;
  const int m0   = ((bid / 96) & 3) * 64;
  const int s    = bid / 384;
  const int K    = HID;
  const int koff = s * KSPL;

  const int fr    = lane & 15;
  const int kb    = (lane >> 4) << 4;
  const int swz   = (fr & 7) << 4;
  const int colp0 = kb ^ swz;
  const int colp1 = (64 | kb) ^ swz;

  const int srow = tid >> 3;
  const int scb  = ((tid & 7) << 4) ^ ((srow & 7) << 4);
  const u16* gA = hbf  + (size_t)(m0 + srow) * K + koff + (scb >> 1);
  const u16* gB = Whhb + (size_t)(n0 + srow) * K + koff + (scb >> 1);
  const int wdst = wid << 10;

  char* ldsA = lds;
  char* ldsB = lds + 16384;
  char* aRowB = ldsA + (wr * 32 + fr) * 128;
  char* bRowB = ldsB + (wc * 32 + fr) * 128;

  float* Cp = HW + (size_t)s * BSZ * GATES;
  const int r0 = (lane >> 4) << 2;
  const int cc = lane & 15;

  const int citem = bid * 128 + (tid & 127);
  const bool cact = tid < 128;

  if (cact)
    cell_item(citem, XW, HW, cbuf, hbf, hs, 1);
  grid.sync();

  for (int f = 1; f < FF; ++f) {
    f32x4 acc[2][2] = {};
    step_gemm_body(gA, gB, K, ldsA, ldsB, aRowB, bRowB, wdst, colp0, colp1, acc);

#pragma unroll
    for (int i = 0; i < 2; ++i)
#pragma unroll
      for (int j = 0; j < 2; ++j) {
        const size_t rbase = (size_t)(m0 + wr * 32 + i * 16 + r0) * GATES +
                             (n0 + wc * 32 + j * 16 + cc);
#pragma unroll
        for (int r = 0; r < 4; ++r)
          Cp[rbase + (size_t)r * GATES] = acc[i][j][r];
      }

    grid.sync();   // HW partials visible grid-wide

    if (cact)
      cell_item(citem, XW + (size_t)f * BSZ * GATES, HW, cbuf, hbf,
                hs + (size_t)f * BSZ * HID, 0);

    grid.sync();   // h (hbf) visible before next gemm phase
  }
}

// ---------------- fallback kernels (R8 path, proven) ----------------
__global__ __launch_bounds__(256, 4) void gemm_step(
    const u16* __restrict__ A, const u16* __restrict__ Bt,
    float* __restrict__ HW) {
  __shared__ __align__(16) char lds[32768];
  const int tid  = threadIdx.x;
  const int lane = tid & 63;
  const int wid  = tid >> 6;
  const int wr   = wid >> 1;
  const int wc   = wid & 1;
  const int n0   = blockIdx.x * 64;
  const int m0   = blockIdx.y * 64;
  const int s    = blockIdx.z;
  const int K    = HID;
  const int koff = s * KSPL;

  const int fr    = lane & 15;
  const int kb    = (lane >> 4) << 4;
  const int swz   = (fr & 7) << 4;
  const int colp0 = kb ^ swz;
  const int colp1 = (64 | kb) ^ swz;

  const int srow = tid >> 3;
  const int scb  = ((tid & 7) << 4) ^ ((srow & 7) << 4);
  const u16* gA = A  + (size_t)(m0 + srow) * K + koff + (scb >> 1);
  const u16* gB = Bt + (size_t)(n0 + srow) * K + koff + (scb >> 1);
  const int wdst = wid << 10;

  char* ldsA = lds;
  char* ldsB = lds + 16384;
  char* aRowB = ldsA + (wr * 32 + fr) * 128;
  char* bRowB = ldsB + (wc * 32 + fr) * 128;

  f32x4 acc[2][2] = {};
  step_gemm_body(gA, gB, K, ldsA, ldsB, aRowB, bRowB, wdst, colp0, colp1, acc);

  float* Cp = HW + (size_t)s * BSZ * GATES;
  const int r0 = (lane >> 4) << 2;
  const int cc = lane & 15;
#pragma unroll
  for (int i = 0; i < 2; ++i)
#pragma unroll
    for (int j = 0; j < 2; ++j) {
      const size_t rbase = (size_t)(m0 + wr * 32 + i * 16 + r0) * GATES +
                           (n0 + wc * 32 + j * 16 + cc);
#pragma unroll
      for (int r = 0; r < 4; ++r)
        Cp[rbase + (size_t)r * GATES] = acc[i][j][r];
    }
}

__global__ void lstm_cell2(const float* __restrict__ XW_f,
                           const float* __restrict__ HWb,
                           float* __restrict__ c,
                           u16* __restrict__ h_bf,
                           float* __restrict__ hs_f,
                           int first) {
  int idx = blockIdx.x * blockDim.x + threadIdx.x;
  cell_item(idx, XW_f, HWb, c, h_bf, hs_f, first);
}

// ---------------- final linear ----------------
__global__ __launch_bounds__(256) void final_k(const float* __restrict__ hs,
                                               const float* __restrict__ lin_W,
                                               const float* __restrict__ lin_b,
                                               float* __restrict__ out) {
  __shared__ float Wsh[12 * 36];
  __shared__ float bsh[12];
  for (int i = threadIdx.x; i < 12 * 36; i += blockDim.x) Wsh[i] = lin_W[i];
  if (threadIdx.x < 12) bsh[threadIdx.x] = lin_b[threadIdx.x];
  __syncthreads();

  int idx = blockIdx.x * blockDim.x + threadIdx.x;
  int b = idx >> 9;
  int n = idx & 511;

  float acc[12];
#pragma unroll
  for (int o = 0; o < 12; ++o) acc[o] = bsh[o];

#pragma unroll
  for (int kk = 0; kk < 3; ++kk)
#pragma unroll
    for (int f = 0; f < 12; ++f) {
      float v = hs[(size_t)(f * BSZ + b) * HID + 3 * n + kk];
      v = fmaxf(v, 0.0f);
      int j = 12 * kk + f;
#pragma unroll
      for (int o = 0; o < 12; ++o) acc[o] += v * Wsh[o * 36 + j];
    }

#pragma unroll
  for (int o = 0; o < 12; ++o) out[(size_t)idx * 12 + o] = acc[o];
}

extern "C" void kernel_launch(void* const* d_in, const int* in_sizes, int n_in,
                              void* d_out, int out_size, void* d_ws, size_t ws_size,
                              hipStream_t stream) {
  (void)in_sizes; (void)n_in; (void)out_size; (void)ws_size;
  const float* X     = (const float*)d_in[1];
  const float* W_ih  = (const float*)d_in[2];
  const float* W_hh  = (const float*)d_in[3];
  const float* b_ih  = (const float*)d_in[4];
  const float* b_hh  = (const float*)d_in[5];
  const float* lin_W = (const float*)d_in[6];
  const float* lin_b = (const float*)d_in[7];
  float* out = (float*)d_out;

  char* p = (char*)d_ws;
  u16*   Ax   = (u16*)p;   p += (size_t)MROWS * INSZ * 2;
  u16*   Wihb = (u16*)p;   p += (size_t)GATES * INSZ * 2;
  u16*   Whhb = (u16*)p;   p += (size_t)GATES * HID * 2;
  float* XW   = (float*)p; p += (size_t)MROWS * GATES * 4;
  p += (size_t)BSZ * GATES * 4;
  u16*   hbf  = (u16*)p;   p += (size_t)BSZ * HID * 2;
  float* cbuf = (float*)p; p += (size_t)BSZ * HID * 4;
  float* hs   = (float*)p; p += (size_t)FF * BSZ * HID * 4;

  float* HW0 = (float*)Ax;   // partials alias dead Ax region

  hipFuncSetAttribute((const void*)gemm8p,
                      hipFuncAttributeMaxDynamicSharedMemorySize, LDS_TOTAL);

  cvt_bf16<<<4096, 256, 0, stream>>>(W_ih, Wihb, (long)GATES * INSZ / 4);
  cvt_bf16<<<2048, 256, 0, stream>>>(W_hh, Whhb, (long)GATES * HID / 4);
  pack_x4<<<(BSZ * INSZ / 4) / 256, 256, 0, stream>>>(X, Ax);

  gemm8p<<<256, 512, LDS_TOTAL, stream>>>(Ax, Wihb, b_ih, b_hh, XW,
                                          MROWS, GATES, INSZ);

  // 3) recurrence: cooperative persistent kernel, with launch-error fallback
  {
    const u16* Whhb_a = Whhb; const float* XW_a = XW; float* HW_a = HW0;
    u16* hbf_a = hbf; float* cbuf_a = cbuf; float* hs_a = hs;
    void* args[] = { (void*)&Whhb_a, (void*)&XW_a, (void*)&HW_a,
                     (void*)&hbf_a, (void*)&cbuf_a, (void*)&hs_a };
    hipError_t cerr = hipLaunchCooperativeKernel(
        (const void*)lstm_persist, dim3(768), dim3(256), args, 0, stream);
    if (cerr != hipSuccess) {
      // proven multi-launch path (R8)
      for (int f = 0; f < FF; ++f) {
        if (f > 0)
          gemm_step<<<dim3(GATES / 64, BSZ / 64, SPLITK), 256, 0, stream>>>(
              hbf, Whhb, HW0);
        lstm_cell2<<<(BSZ * HID / 4) / 256, 256, 0, stream>>>(
            XW + (size_t)f * BSZ * GATES, HW0, cbuf, hbf,
            hs + (size_t)f * BSZ * HID, f == 0 ? 1 : 0);
      }
    }
  }

  final_k<<<(BSZ * NN) / 256, 256, 0, stream>>>(hs, lin_W, lin_b, out);
}

// Round 12
// 438.620 us; speedup vs baseline: 5.5730x; 5.5730x over previous
//
#include <hip/hip_runtime.h>
#include <hip/hip_bf16.h>
#include <stdint.h>

typedef uint16_t u16;
typedef __attribute__((ext_vector_type(8))) __bf16 bf16x8;
typedef __attribute__((ext_vector_type(4))) float f32x4;
typedef __attribute__((ext_vector_type(4))) u16 u16x4;

// Problem constants
#define BSZ   256
#define NN    512
#define TT    12
#define FF    12
#define HID   1536
#define INSZ  6144    // N*F = LSTM input size
#define GATES 6144    // 4*HID
#define MROWS 3072    // FF*BSZ rows of the hoisted input GEMM

static __device__ __forceinline__ u16 f2bf(float x) {
  uint32_t u = __builtin_bit_cast(uint32_t, x);
  u += 0x7fffu + ((u >> 16) & 1u);   // RNE
  return (u16)(u >> 16);
}

static __device__ __forceinline__ float sigm(float x) {
  return 1.0f / (1.0f + expf(-x));
}

// ---------------- fp32 -> bf16 convert + gate-interleave row permute ----------------
// out row' = 4*(r%HID) + r/HID  (orig row r = g*HID + j  ->  row' = 4j+g)
__global__ void cvt_perm(const float* __restrict__ in, u16* __restrict__ out,
                         int ncol4) {
  long idx = (long)blockIdx.x * blockDim.x + threadIdx.x;   // r*ncol4 + c4
  int r  = (int)(idx / ncol4);
  int c4 = (int)(idx - (long)r * ncol4);
  int rp = ((r % HID) << 2) + r / HID;
  float4 v = ((const float4*)in)[idx];
  u16x4 w = { f2bf(v.x), f2bf(v.y), f2bf(v.z), f2bf(v.w) };
  ((u16x4*)out)[(size_t)rp * ncol4 + c4] = w;
}

// ---------------- pack X: 4 k's per thread -> coalesced u16x4 writes ----------------
__global__ void pack_x4(const float* __restrict__ X, u16* __restrict__ Ax) {
  int idx = blockIdx.x * blockDim.x + threadIdx.x;   // (b, k4), k4 in [0,1536)
  int b  = idx / (INSZ / 4);
  int k4 = idx - b * (INSZ / 4);
  const float* xp = X + (size_t)b * (INSZ * FF) + (size_t)k4 * (4 * FF);
  float4 v[12];   // 48 floats = [kk 0..3][f 0..11]
#pragma unroll
  for (int j = 0; j < 12; ++j) v[j] = ((const float4*)xp)[j];
  const float* vf = (const float*)v;
#pragma unroll
  for (int f = 0; f < FF; ++f) {
    u16x4 w = { f2bf(vf[0 * FF + f]), f2bf(vf[1 * FF + f]),
                f2bf(vf[2 * FF + f]), f2bf(vf[3 * FF + f]) };
    *(u16x4*)&Ax[(size_t)(f * BSZ + b) * INSZ + k4 * 4] = w;
  }
}

// =====================================================================
// Deep-pipelined bf16 GEMM (R8 structure, 212 us). B rows are
// gate-interleaved, so C cols are too; bias fetch un-permutes.
// =====================================================================
#define BM8 192
#define BN8 384
#define LDSA_SZ 24576
#define LDSB_SZ 49152
#define LDS_TOTAL (2 * (LDSA_SZ + LDSB_SZ))   // 147456

#define GLL(src, dst)                                                          \
  __builtin_amdgcn_global_load_lds(                                            \
      (const __attribute__((address_space(1))) void*)(src),                    \
      (__attribute__((address_space(3))) void*)(dst), 16, 0, 0)

#define SBAR() asm volatile("s_barrier" ::: "memory")
#define SCHED_FENCE_DS() __builtin_amdgcn_sched_barrier(0x7F)
#define WAIT_LGKM0()                                                           \
  do {                                                                         \
    asm volatile("s_waitcnt lgkmcnt(0)" ::: "memory");                         \
    __builtin_amdgcn_sched_barrier(0);                                         \
  } while (0)

__global__ __launch_bounds__(512, 1) void gemm8p(
    const u16* __restrict__ A, const u16* __restrict__ Bt,
    const float* __restrict__ bi, const float* __restrict__ bh,
    float* __restrict__ C, int M, int N, int K) {
  extern __shared__ __align__(16) char lds[];
  const int tid  = threadIdx.x;
  const int lane = tid & 63;
  const int wid  = tid >> 6;
  const int wr   = wid >> 2;
  const int wc   = wid & 3;

  const int nbx  = N / BN8;
  const int cpx  = gridDim.x >> 3;
  const int orig = blockIdx.x;
  const int wgid = (orig & 7) * cpx + (orig >> 3);
  const int m0   = (wgid / nbx) * BM8;
  const int n0   = (wgid % nbx) * BN8;

  const int fr    = lane & 15;
  const int kb    = (lane >> 4) << 4;
  const int swz   = (fr & 7) << 4;
  const int colp0 = kb ^ swz;
  const int colp1 = (64 | kb) ^ swz;

  const int srow = tid >> 3;
  const int scb  = ((tid & 7) << 4) ^ ((srow & 7) << 4);
  const u16* gA = A  + (size_t)(m0 + srow) * K + (scb >> 1);
  const u16* gB = Bt + (size_t)(n0 + srow) * K + (scb >> 1);
  const int wdst = wid << 10;

  char* ldsA = lds;
  char* ldsB = lds + 2 * LDSA_SZ;
  char* aRowB = ldsA + (wr * 96 + fr) * 128;
  char* bRowB = ldsB + (wc * 96 + fr) * 128;

  f32x4 acc[6][6] = {};
  const int NT = K >> 6;

#pragma unroll
  for (int c = 0; c < 3; ++c) GLL(gA + (size_t)c * 64 * K, ldsA + c * 8192 + wdst);
#pragma unroll
  for (int c = 0; c < 6; ++c) GLL(gB + (size_t)c * 64 * K, ldsB + c * 8192 + wdst);

  for (int t = 0; t < NT; ++t) {
    const int p = t & 1;
    char* aRow = aRowB + p * LDSA_SZ;
    char* bRow = bRowB + p * LDSB_SZ;
    char* An = ldsA + (p ^ 1) * LDSA_SZ;
    char* Bn = ldsB + (p ^ 1) * LDSB_SZ;
    const u16* gAn = gA + (size_t)(t + 1) * 64;
    const u16* gBn = gB + (size_t)(t + 1) * 64;
    const bool pf = (t + 1 < NT);

    bf16x8 a0[2][3], a1[2][3], b0[2][3], b1[2][3];

    if (pf) {
#pragma unroll
      for (int c = 0; c < 3; ++c) GLL(gAn + (size_t)c * 64 * K, An + c * 8192 + wdst);
      asm volatile("s_waitcnt vmcnt(3)" ::: "memory");
    } else {
      asm volatile("s_waitcnt vmcnt(0)" ::: "memory");
    }
    SBAR();

#pragma unroll
    for (int i = 0; i < 3; ++i) {
      a0[0][i] = *(const bf16x8*)(aRow + i * 2048 + colp0);
      a0[1][i] = *(const bf16x8*)(aRow + i * 2048 + colp1);
      b0[0][i] = *(const bf16x8*)(bRow + i * 2048 + colp0);
      b0[1][i] = *(const bf16x8*)(bRow + i * 2048 + colp1);
    }
    __builtin_amdgcn_s_setprio(1);
#pragma unroll
    for (int i = 0; i < 3; ++i)
#pragma unroll
      for (int j = 0; j < 3; ++j) {
        acc[i][j] = __builtin_amdgcn_mfma_f32_16x16x32_bf16(a0[0][i], b0[0][j], acc[i][j], 0, 0, 0);
        acc[i][j] = __builtin_amdgcn_mfma_f32_16x16x32_bf16(a0[1][i], b0[1][j], acc[i][j], 0, 0, 0);
      }
    __builtin_amdgcn_s_setprio(0);
    if (pf) {
      GLL(gBn + (size_t)0 * 64 * K, Bn + 0 * 8192 + wdst);
      GLL(gBn + (size_t)1 * 64 * K, Bn + 1 * 8192 + wdst);
    }
    SCHED_FENCE_DS();

#pragma unroll
    for (int i = 0; i < 3; ++i) {
      b1[0][i] = *(const bf16x8*)(bRow + (3 + i) * 2048 + colp0);
      b1[1][i] = *(const bf16x8*)(bRow + (3 + i) * 2048 + colp1);
    }
    __builtin_amdgcn_s_setprio(1);
#pragma unroll
    for (int i = 0; i < 3; ++i)
#pragma unroll
      for (int j = 0; j < 3; ++j) {
        acc[i][3 + j] = __builtin_amdgcn_mfma_f32_16x16x32_bf16(a0[0][i], b1[0][j], acc[i][3 + j], 0, 0, 0);
        acc[i][3 + j] = __builtin_amdgcn_mfma_f32_16x16x32_bf16(a0[1][i], b1[1][j], acc[i][3 + j], 0, 0, 0);
      }
    __builtin_amdgcn_s_setprio(0);
    if (pf) {
      GLL(gBn + (size_t)2 * 64 * K, Bn + 2 * 8192 + wdst);
      GLL(gBn + (size_t)3 * 64 * K, Bn + 3 * 8192 + wdst);
    }
    SCHED_FENCE_DS();

#pragma unroll
    for (int i = 0; i < 3; ++i) {
      a1[0][i] = *(const bf16x8*)(aRow + (3 + i) * 2048 + colp0);
      a1[1][i] = *(const bf16x8*)(aRow + (3 + i) * 2048 + colp1);
    }
    __builtin_amdgcn_s_setprio(1);
#pragma unroll
    for (int i = 0; i < 3; ++i)
#pragma unroll
      for (int j = 0; j < 3; ++j) {
        acc[3 + i][3 + j] = __builtin_amdgcn_mfma_f32_16x16x32_bf16(a1[0][i], b1[0][j], acc[3 + i][3 + j], 0, 0, 0);
        acc[3 + i][3 + j] = __builtin_amdgcn_mfma_f32_16x16x32_bf16(a1[1][i], b1[1][j], acc[3 + i][3 + j], 0, 0, 0);
      }
    __builtin_amdgcn_s_setprio(0);
    if (pf) {
      GLL(gBn + (size_t)4 * 64 * K, Bn + 4 * 8192 + wdst);
      GLL(gBn + (size_t)5 * 64 * K, Bn + 5 * 8192 + wdst);
    }
    SCHED_FENCE_DS();

    __builtin_amdgcn_s_setprio(1);
#pragma unroll
    for (int i = 0; i < 3; ++i)
#pragma unroll
      for (int j = 0; j < 3; ++j) {
        acc[3 + i][j] = __builtin_amdgcn_mfma_f32_16x16x32_bf16(a1[0][i], b0[0][j], acc[3 + i][j], 0, 0, 0);
        acc[3 + i][j] = __builtin_amdgcn_mfma_f32_16x16x32_bf16(a1[1][i], b0[1][j], acc[3 + i][j], 0, 0, 0);
      }
    __builtin_amdgcn_s_setprio(0);

    SBAR();
  }

  const int r0 = (lane >> 4) << 2;
  const int cc = lane & 15;
#pragma unroll
  for (int j = 0; j < 6; ++j) {
    const int col = n0 + wc * 96 + j * 16 + cc;          // interleaved position
    const int oc  = (col & 3) * HID + (col >> 2);        // original gate index
    const float bv = bi[oc] + bh[oc];
#pragma unroll
    for (int i = 0; i < 6; ++i) {
      const size_t rbase = (size_t)(m0 + wr * 96 + i * 16 + r0) * N + col;
#pragma unroll
      for (int r = 0; r < 4; ++r)
        C[rbase + (size_t)r * N] = acc[i][j][r] + bv;
    }
  }
}

// =====================================================================
// Fused step: HW-tile GEMM (64x64, K=1536, NT=24, dbuf, counted vmcnt)
// + LSTM cell in the epilogue (gates are LDS-local thanks to the
// gate-interleaved weight layout). Grid (96,4) = 384 blocks.
// hbf is double-buffered across steps (in != out) to avoid the
// cross-block read/write race on h.
// =====================================================================
__global__ __launch_bounds__(256, 4) void gemm_cell(
    const u16* __restrict__ hbf_in,    // (256 x 1536) bf16 h(t-1)
    const u16* __restrict__ Whhb,      // (6144 x 1536) bf16, rows interleaved
    const float* __restrict__ XW_f,    // (256 x 6144) interleaved, biases in
    float* __restrict__ cbuf,          // (256 x 1536) c state (in-place)
    u16* __restrict__ hbf_out,         // (256 x 1536) bf16 h(t)
    float* __restrict__ hs_f) {        // (256 x 1536) fp32 h(t) slice
  __shared__ __align__(16) char lds[32768];
  const int tid  = threadIdx.x;
  const int lane = tid & 63;
  const int wid  = tid >> 6;
  const int wr   = wid >> 1;   // 0..1
  const int wc   = wid & 1;    // 0..1
  const int n0   = blockIdx.x * 64;   // interleaved col base
  const int m0   = blockIdx.y * 64;   // batch base
  const int K    = HID;

  const int fr    = lane & 15;
  const int kb    = (lane >> 4) << 4;
  const int swz   = (fr & 7) << 4;
  const int colp0 = kb ^ swz;
  const int colp1 = (64 | kb) ^ swz;

  const int srow = tid >> 3;
  const int scb  = ((tid & 7) << 4) ^ ((srow & 7) << 4);
  const u16* gA = hbf_in + (size_t)(m0 + srow) * K + (scb >> 1);
  const u16* gB = Whhb   + (size_t)(n0 + srow) * K + (scb >> 1);
  const int wdst = wid << 10;

  char* ldsA = lds;            // [2][8192]
  char* ldsB = lds + 16384;    // [2][8192]
  char* aRowB = ldsA + (wr * 32 + fr) * 128;
  char* bRowB = ldsB + (wc * 32 + fr) * 128;

  f32x4 acc[2][2] = {};
  const int NT = K >> 6;   // 24

  GLL(gA,                  ldsA + wdst);
  GLL(gA + (size_t)32 * K, ldsA + 4096 + wdst);
  GLL(gB,                  ldsB + wdst);
  GLL(gB + (size_t)32 * K, ldsB + 4096 + wdst);

  for (int t = 0; t < NT; ++t) {
    const int p = t & 1;
    char* aRow = aRowB + p * 8192;
    char* bRow = bRowB + p * 8192;
    char* An = ldsA + (p ^ 1) * 8192;
    char* Bn = ldsB + (p ^ 1) * 8192;
    const u16* gAn = gA + (size_t)(t + 1) * 64;
    const u16* gBn = gB + (size_t)(t + 1) * 64;

    if (t + 1 < NT) {
      GLL(gAn,                  An + wdst);
      GLL(gAn + (size_t)32 * K, An + 4096 + wdst);
      GLL(gBn,                  Bn + wdst);
      GLL(gBn + (size_t)32 * K, Bn + 4096 + wdst);
      asm volatile("s_waitcnt vmcnt(4)" ::: "memory");
    } else {
      asm volatile("s_waitcnt vmcnt(0)" ::: "memory");
    }
    SBAR();

    bf16x8 a[2][2], b[2][2];
#pragma unroll
    for (int i = 0; i < 2; ++i) {
      a[0][i] = *(const bf16x8*)(aRow + i * 2048 + colp0);
      a[1][i] = *(const bf16x8*)(aRow + i * 2048 + colp1);
      b[0][i] = *(const bf16x8*)(bRow + i * 2048 + colp0);
      b[1][i] = *(const bf16x8*)(bRow + i * 2048 + colp1);
    }
    WAIT_LGKM0();
    __builtin_amdgcn_s_setprio(1);
#pragma unroll
    for (int i = 0; i < 2; ++i)
#pragma unroll
      for (int j = 0; j < 2; ++j) {
        acc[i][j] = __builtin_amdgcn_mfma_f32_16x16x32_bf16(a[0][i], b[0][j], acc[i][j], 0, 0, 0);
        acc[i][j] = __builtin_amdgcn_mfma_f32_16x16x32_bf16(a[1][i], b[1][j], acc[i][j], 0, 0, 0);
      }
    __builtin_amdgcn_s_setprio(0);
    SBAR();
  }

  // ---- epilogue: acc -> LDS (stride 68 floats kills bank conflicts) ----
  float* sacc = (float*)lds;   // [64][68], 17408 B <= 32768, gemm bufs dead
  const int r0 = (lane >> 4) << 2;
  const int cc = lane & 15;
#pragma unroll
  for (int i = 0; i < 2; ++i)
#pragma unroll
    for (int j = 0; j < 2; ++j) {
      const int ml = wr * 32 + i * 16 + r0;
      const int nl = wc * 32 + j * 16 + cc;
#pragma unroll
      for (int r = 0; r < 4; ++r)
        sacc[(ml + r) * 68 + nl] = acc[i][j][r];
    }
  __syncthreads();

  // ---- cell: 64 batch x 16 j's; gates i,f,g,o = interleaved cols 4j+0..3
  for (int it = tid; it < 1024; it += 256) {
    const int bl = it >> 4;                 // local batch 0..63
    const int jl = it & 15;                 // local j 0..15
    const int b  = m0 + bl;
    const int jg = (n0 >> 2) + jl;          // global j
    const float4 hw = *(const float4*)&sacc[bl * 68 + jl * 4];
    const float4 xw = *(const float4*)&XW_f[(size_t)b * GATES + n0 + jl * 4];
    const float gi = xw.x + hw.x;
    const float gf = xw.y + hw.y;
    const float gg = xw.z + hw.z;
    const float go = xw.w + hw.w;
    const int cidx = b * HID + jg;
    const float cp = cbuf[cidx];
    const float cv = sigm(gf) * cp + sigm(gi) * tanhf(gg);
    const float h  = tanhf(sigm(go) * tanhf(cv));
    cbuf[cidx]    = cv;
    hbf_out[cidx] = f2bf(h);
    hs_f[cidx]    = h;
  }
}

// ---------------- first step: gates = XW' only (biases included) ----------------
__global__ void cell_first(const float* __restrict__ XW,
                           float* __restrict__ cbuf,
                           u16* __restrict__ hbf_out,
                           float* __restrict__ hs_f) {
  int it = blockIdx.x * blockDim.x + threadIdx.x;   // 256*1536 items
  int b = it / HID;
  int j = it - b * HID;
  const float4 xw = *(const float4*)&XW[(size_t)b * GATES + 4 * j];
  const float cv = sigm(xw.x) * tanhf(xw.z);        // f-gate * 0 dropped
  const float h  = tanhf(sigm(xw.w) * tanhf(cv));
  cbuf[it]    = cv;
  hbf_out[it] = f2bf(h);
  hs_f[it]    = h;
}

// ---------------- final: out[b,n,o] = relu(out2[b,n,:]) @ lin_W^T + lin_b ----------------
__global__ __launch_bounds__(256) void final_k(const float* __restrict__ hs,
                                               const float* __restrict__ lin_W,
                                               const float* __restrict__ lin_b,
                                               float* __restrict__ out) {
  __shared__ float Wsh[12 * 36];
  __shared__ float bsh[12];
  for (int i = threadIdx.x; i < 12 * 36; i += blockDim.x) Wsh[i] = lin_W[i];
  if (threadIdx.x < 12) bsh[threadIdx.x] = lin_b[threadIdx.x];
  __syncthreads();

  int idx = blockIdx.x * blockDim.x + threadIdx.x;
  int b = idx >> 9;
  int n = idx & 511;

  float acc[12];
#pragma unroll
  for (int o = 0; o < 12; ++o) acc[o] = bsh[o];

#pragma unroll
  for (int kk = 0; kk < 3; ++kk)
#pragma unroll
    for (int f = 0; f < 12; ++f) {
      float v = hs[(size_t)(f * BSZ + b) * HID + 3 * n + kk];
      v = fmaxf(v, 0.0f);
      int j = 12 * kk + f;
#pragma unroll
      for (int o = 0; o < 12; ++o) acc[o] += v * Wsh[o * 36 + j];
    }

#pragma unroll
  for (int o = 0; o < 12; ++o) out[(size_t)idx * 12 + o] = acc[o];
}

extern "C" void kernel_launch(void* const* d_in, const int* in_sizes, int n_in,
                              void* d_out, int out_size, void* d_ws, size_t ws_size,
                              hipStream_t stream) {
  (void)in_sizes; (void)n_in; (void)out_size; (void)ws_size;
  const float* X     = (const float*)d_in[1];
  const float* W_ih  = (const float*)d_in[2];
  const float* W_hh  = (const float*)d_in[3];
  const float* b_ih  = (const float*)d_in[4];
  const float* b_hh  = (const float*)d_in[5];
  const float* lin_W = (const float*)d_in[6];
  const float* lin_b = (const float*)d_in[7];
  float* out = (float*)d_out;

  char* p = (char*)d_ws;
  u16*   Ax   = (u16*)p;   p += (size_t)MROWS * INSZ * 2;
  u16*   Wihb = (u16*)p;   p += (size_t)GATES * INSZ * 2;
  u16*   Whhb = (u16*)p;   p += (size_t)GATES * HID * 2;
  float* XW   = (float*)p; p += (size_t)MROWS * GATES * 4;
  u16*   hbfA = (u16*)p;   p += (size_t)BSZ * HID * 2;
  u16*   hbfB = (u16*)p;   p += (size_t)BSZ * HID * 2;
  float* cbuf = (float*)p; p += (size_t)BSZ * HID * 4;
  float* hs   = (float*)p; p += (size_t)FF * BSZ * HID * 4;

  hipFuncSetAttribute((const void*)gemm8p,
                      hipFuncAttributeMaxDynamicSharedMemorySize, LDS_TOTAL);

  // 1) convert weights (gate-interleaved rows) + pack X
  cvt_perm<<<(GATES * (INSZ / 4)) / 256, 256, 0, stream>>>(W_ih, Wihb, INSZ / 4);
  cvt_perm<<<(GATES * (HID / 4)) / 256, 256, 0, stream>>>(W_hh, Whhb, HID / 4);
  pack_x4<<<(BSZ * INSZ / 4) / 256, 256, 0, stream>>>(X, Ax);

  // 2) hoisted input GEMM: XW (interleaved cols) = Ax @ Wihb^T + biases
  gemm8p<<<256, 512, LDS_TOTAL, stream>>>(Ax, Wihb, b_ih, b_hh, XW,
                                          MROWS, GATES, INSZ);

  // 3) recurrence: fused GEMM+cell per step, hbf double-buffered
  u16* bufs[2] = { hbfA, hbfB };
  cell_first<<<(BSZ * HID) / 256, 256, 0, stream>>>(XW, cbuf, bufs[0], hs);
  for (int f = 1; f < FF; ++f) {
    gemm_cell<<<dim3(96, 4), 256, 0, stream>>>(
        bufs[(f - 1) & 1], Whhb, XW + (size_t)f * BSZ * GATES, cbuf,
        bufs[f & 1], hs + (size_t)f * BSZ * HID);
  }

  // 4) final linear
  final_k<<<(BSZ * NN) / 256, 256, 0, stream>>>(hs, lin_W, lin_b, out);
}

// Round 13
// 431.287 us; speedup vs baseline: 5.6678x; 1.0170x over previous
//
#include <hip/hip_runtime.h>
#include <hip/hip_bf16.h>
#include <stdint.h>

typedef uint16_t u16;
typedef __attribute__((ext_vector_type(8))) __bf16 bf16x8;
typedef __attribute__((ext_vector_type(4))) float f32x4;
typedef __attribute__((ext_vector_type(4))) u16 u16x4;

// Problem constants
#define BSZ   256
#define NN    512
#define TT    12
#define FF    12
#define HID   1536
#define INSZ  6144    // N*F = LSTM input size
#define GATES 6144    // 4*HID
#define MROWS 3072    // FF*BSZ rows of the hoisted input GEMM

static __device__ __forceinline__ u16 f2bf(float x) {
  uint32_t u = __builtin_bit_cast(uint32_t, x);
  u += 0x7fffu + ((u >> 16) & 1u);   // RNE
  return (u16)(u >> 16);
}

static __device__ __forceinline__ float sigm(float x) {
  return 1.0f / (1.0f + expf(-x));
}

// ---------------- fp32 -> bf16 convert + gate-interleave row permute ----------------
// out row' = 4*(r%HID) + r/HID  (orig row r = g*HID + j  ->  row' = 4j+g)
__global__ void cvt_perm(const float* __restrict__ in, u16* __restrict__ out,
                         int ncol4) {
  long idx = (long)blockIdx.x * blockDim.x + threadIdx.x;   // r*ncol4 + c4
  int r  = (int)(idx / ncol4);
  int c4 = (int)(idx - (long)r * ncol4);
  int rp = ((r % HID) << 2) + r / HID;
  float4 v = ((const float4*)in)[idx];
  u16x4 w = { f2bf(v.x), f2bf(v.y), f2bf(v.z), f2bf(v.w) };
  ((u16x4*)out)[(size_t)rp * ncol4 + c4] = w;
}

// ---------------- pack X: 4 k's per thread -> coalesced u16x4 writes ----------------
__global__ void pack_x4(const float* __restrict__ X, u16* __restrict__ Ax) {
  int idx = blockIdx.x * blockDim.x + threadIdx.x;   // (b, k4), k4 in [0,1536)
  int b  = idx / (INSZ / 4);
  int k4 = idx - b * (INSZ / 4);
  const float* xp = X + (size_t)b * (INSZ * FF) + (size_t)k4 * (4 * FF);
  float4 v[12];   // 48 floats = [kk 0..3][f 0..11]
#pragma unroll
  for (int j = 0; j < 12; ++j) v[j] = ((const float4*)xp)[j];
  const float* vf = (const float*)v;
#pragma unroll
  for (int f = 0; f < FF; ++f) {
    u16x4 w = { f2bf(vf[0 * FF + f]), f2bf(vf[1 * FF + f]),
                f2bf(vf[2 * FF + f]), f2bf(vf[3 * FF + f]) };
    *(u16x4*)&Ax[(size_t)(f * BSZ + b) * INSZ + k4 * 4] = w;
  }
}

// =====================================================================
// Deep-pipelined bf16 GEMM. R13: one-group-ahead read skew at half-k
// granularity — 8 phases of {read 3 frags for cluster k+1 ; 9-MFMA
// cluster k}. Peak 4 half-sets live (48 VGPR) + 144 acc < 256 cap.
// Tile 192x384, BK=64, 512 threads (8 waves, 2x4), 2 barriers/K-tile.
// =====================================================================
#define BM8 192
#define BN8 384
#define LDSA_SZ 24576
#define LDSB_SZ 49152
#define LDS_TOTAL (2 * (LDSA_SZ + LDSB_SZ))   // 147456

#define GLL(src, dst)                                                          \
  __builtin_amdgcn_global_load_lds(                                            \
      (const __attribute__((address_space(1))) void*)(src),                    \
      (__attribute__((address_space(3))) void*)(dst), 16, 0, 0)

#define SBAR() asm volatile("s_barrier" ::: "memory")
#define SCHED_FENCE_DS() __builtin_amdgcn_sched_barrier(0x7F)
#define WAIT_LGKM0()                                                           \
  do {                                                                         \
    asm volatile("s_waitcnt lgkmcnt(0)" ::: "memory");                         \
    __builtin_amdgcn_sched_barrier(0);                                         \
  } while (0)

#define MFMA9(AF, BF, RO, CO)                                                  \
  do {                                                                         \
    __builtin_amdgcn_s_setprio(1);                                             \
    _Pragma("unroll") for (int i = 0; i < 3; ++i)                              \
        _Pragma("unroll") for (int j = 0; j < 3; ++j)                          \
            acc[RO + i][CO + j] = __builtin_amdgcn_mfma_f32_16x16x32_bf16(     \
                AF[i], BF[j], acc[RO + i][CO + j], 0, 0, 0);                   \
    __builtin_amdgcn_s_setprio(0);                                             \
  } while (0)

__global__ __launch_bounds__(512, 1) void gemm8p(
    const u16* __restrict__ A, const u16* __restrict__ Bt,
    const float* __restrict__ bi, const float* __restrict__ bh,
    float* __restrict__ C, int M, int N, int K) {
  extern __shared__ __align__(16) char lds[];
  const int tid  = threadIdx.x;
  const int lane = tid & 63;
  const int wid  = tid >> 6;
  const int wr   = wid >> 2;
  const int wc   = wid & 3;

  const int nbx  = N / BN8;
  const int cpx  = gridDim.x >> 3;
  const int orig = blockIdx.x;
  const int wgid = (orig & 7) * cpx + (orig >> 3);
  const int m0   = (wgid / nbx) * BM8;
  const int n0   = (wgid % nbx) * BN8;

  const int fr    = lane & 15;
  const int kb    = (lane >> 4) << 4;
  const int swz   = (fr & 7) << 4;
  const int colp0 = kb ^ swz;
  const int colp1 = (64 | kb) ^ swz;

  const int srow = tid >> 3;
  const int scb  = ((tid & 7) << 4) ^ ((srow & 7) << 4);
  const u16* gA = A  + (size_t)(m0 + srow) * K + (scb >> 1);
  const u16* gB = Bt + (size_t)(n0 + srow) * K + (scb >> 1);
  const int wdst = wid << 10;

  char* ldsA = lds;
  char* ldsB = lds + 2 * LDSA_SZ;
  char* aRowB = ldsA + (wr * 96 + fr) * 128;
  char* bRowB = ldsB + (wc * 96 + fr) * 128;

  f32x4 acc[6][6] = {};
  const int NT = K >> 6;

#pragma unroll
  for (int c = 0; c < 3; ++c) GLL(gA + (size_t)c * 64 * K, ldsA + c * 8192 + wdst);
#pragma unroll
  for (int c = 0; c < 6; ++c) GLL(gB + (size_t)c * 64 * K, ldsB + c * 8192 + wdst);

  for (int t = 0; t < NT; ++t) {
    const int p = t & 1;
    char* aRow = aRowB + p * LDSA_SZ;
    char* bRow = bRowB + p * LDSB_SZ;
    char* An = ldsA + (p ^ 1) * LDSA_SZ;
    char* Bn = ldsB + (p ^ 1) * LDSB_SZ;
    const u16* gAn = gA + (size_t)(t + 1) * 64;
    const u16* gBn = gB + (size_t)(t + 1) * 64;
    const bool pf = (t + 1 < NT);

    bf16x8 a0[2][3], a1[2][3], b0[2][3], b1[2][3];

    // ---- iter entry: stage A(t+1); wait tile t staged; visibility barrier
    if (pf) {
#pragma unroll
      for (int c = 0; c < 3; ++c) GLL(gAn + (size_t)c * 64 * K, An + c * 8192 + wdst);
      asm volatile("s_waitcnt vmcnt(3)" ::: "memory");
    } else {
      asm volatile("s_waitcnt vmcnt(0)" ::: "memory");
    }
    SBAR();

    // ---- p0: read a0k0 + b0k0 (operands of first cluster)
#pragma unroll
    for (int i = 0; i < 3; ++i) {
      a0[0][i] = *(const bf16x8*)(aRow + i * 2048 + colp0);
      b0[0][i] = *(const bf16x8*)(bRow + i * 2048 + colp0);
    }
    // ---- p1: read b1k0 ; q00k0
#pragma unroll
    for (int i = 0; i < 3; ++i) b1[0][i] = *(const bf16x8*)(bRow + (3 + i) * 2048 + colp0);
    MFMA9(a0[0], b0[0], 0, 0);
    if (pf) {
      GLL(gBn + (size_t)0 * 64 * K, Bn + 0 * 8192 + wdst);
      GLL(gBn + (size_t)1 * 64 * K, Bn + 1 * 8192 + wdst);
    }
    SCHED_FENCE_DS();

    // ---- p2: read a1k0 ; q01k0
#pragma unroll
    for (int i = 0; i < 3; ++i) a1[0][i] = *(const bf16x8*)(aRow + (3 + i) * 2048 + colp0);
    MFMA9(a0[0], b1[0], 0, 3);
    if (pf) {
      GLL(gBn + (size_t)2 * 64 * K, Bn + 2 * 8192 + wdst);
      GLL(gBn + (size_t)3 * 64 * K, Bn + 3 * 8192 + wdst);
    }
    SCHED_FENCE_DS();

    // ---- p3: read a0k1 ; q11k0
#pragma unroll
    for (int i = 0; i < 3; ++i) a0[1][i] = *(const bf16x8*)(aRow + i * 2048 + colp1);
    MFMA9(a1[0], b1[0], 3, 3);
    if (pf) {
      GLL(gBn + (size_t)4 * 64 * K, Bn + 4 * 8192 + wdst);
      GLL(gBn + (size_t)5 * 64 * K, Bn + 5 * 8192 + wdst);
    }
    SCHED_FENCE_DS();

    // ---- p4: read b0k1 ; q10k0
#pragma unroll
    for (int i = 0; i < 3; ++i) b0[1][i] = *(const bf16x8*)(bRow + i * 2048 + colp1);
    MFMA9(a1[0], b0[0], 3, 0);
    SCHED_FENCE_DS();

    // ---- p5: read b1k1 ; q00k1
#pragma unroll
    for (int i = 0; i < 3; ++i) b1[1][i] = *(const bf16x8*)(bRow + (3 + i) * 2048 + colp1);
    MFMA9(a0[1], b0[1], 0, 0);
    SCHED_FENCE_DS();

    // ---- p6: read a1k1 ; q01k1
#pragma unroll
    for (int i = 0; i < 3; ++i) a1[1][i] = *(const bf16x8*)(aRow + (3 + i) * 2048 + colp1);
    MFMA9(a0[1], b1[1], 0, 3);
    SCHED_FENCE_DS();

    // ---- p7: q11k1 ; q10k1
    MFMA9(a1[1], b1[1], 3, 3);
    MFMA9(a1[1], b0[1], 3, 0);

    SBAR();
  }

  const int r0 = (lane >> 4) << 2;
  const int cc = lane & 15;
#pragma unroll
  for (int j = 0; j < 6; ++j) {
    const int col = n0 + wc * 96 + j * 16 + cc;          // interleaved position
    const int oc  = (col & 3) * HID + (col >> 2);        // original gate index
    const float bv = bi[oc] + bh[oc];
#pragma unroll
    for (int i = 0; i < 6; ++i) {
      const size_t rbase = (size_t)(m0 + wr * 96 + i * 16 + r0) * N + col;
#pragma unroll
      for (int r = 0; r < 4; ++r)
        C[rbase + (size_t)r * N] = acc[i][j][r] + bv;
    }
  }
}

// =====================================================================
// Fused step (R13: BK=128, NT=12 — halved latency chain; LDS 64KB dbuf,
// vmcnt(8)). 64x64 tile, 4 waves, grid (96,4) = 384 blocks.
// Gate-interleaved layout -> cell in epilogue. hbf double-buffered.
// =====================================================================
__global__ __launch_bounds__(256, 2) void gemm_cell(
    const u16* __restrict__ hbf_in,    // (256 x 1536) bf16 h(t-1)
    const u16* __restrict__ Whhb,      // (6144 x 1536) bf16, rows interleaved
    const float* __restrict__ XW_f,    // (256 x 6144) interleaved, biases in
    float* __restrict__ cbuf,          // (256 x 1536) c state (in-place)
    u16* __restrict__ hbf_out,         // (256 x 1536) bf16 h(t)
    float* __restrict__ hs_f) {        // (256 x 1536) fp32 h(t) slice
  __shared__ __align__(16) char lds[65536];   // A dbuf 32K + B dbuf 32K
  const int tid  = threadIdx.x;
  const int lane = tid & 63;
  const int wid  = tid >> 6;
  const int wr   = wid >> 1;   // 0..1
  const int wc   = wid & 1;    // 0..1
  const int n0   = blockIdx.x * 64;   // interleaved col base
  const int m0   = blockIdx.y * 64;   // batch base
  const int K    = HID;

  const int fr  = lane & 15;
  const int kb  = (lane >> 4) << 4;
  const int swz = (fr & 7) << 4;
  int colp[4];
#pragma unroll
  for (int k = 0; k < 4; ++k) colp[k] = (k * 64 + kb) ^ swz;

  // staging: thread t -> row = t>>4 (0..15), cb = (t&15)*16 ^ swz(row); chunk c adds 16 rows
  const int srow = tid >> 4;
  const int scb  = ((tid & 15) << 4) ^ ((srow & 7) << 4);
  const u16* gA = hbf_in + (size_t)(m0 + srow) * K + (scb >> 1);
  const u16* gB = Whhb   + (size_t)(n0 + srow) * K + (scb >> 1);
  const int wdst = wid << 10;

  char* ldsA = lds;            // [2][16384], row stride 256 B
  char* ldsB = lds + 32768;    // [2][16384]
  char* aRowB = ldsA + (wr * 32 + fr) * 256;
  char* bRowB = ldsB + (wc * 32 + fr) * 256;

  f32x4 acc[2][2] = {};
  const int NT = K >> 7;   // 12

  // prologue: stage tile 0 into buffer 0 (4 chunks per matrix)
#pragma unroll
  for (int c = 0; c < 4; ++c) {
    GLL(gA + (size_t)c * 16 * K, ldsA + c * 4096 + wdst);
    GLL(gB + (size_t)c * 16 * K, ldsB + c * 4096 + wdst);
  }

  for (int t = 0; t < NT; ++t) {
    const int p = t & 1;
    char* aRow = aRowB + p * 16384;
    char* bRow = bRowB + p * 16384;
    char* An = ldsA + (p ^ 1) * 16384;
    char* Bn = ldsB + (p ^ 1) * 16384;
    const u16* gAn = gA + (size_t)(t + 1) * 128;
    const u16* gBn = gB + (size_t)(t + 1) * 128;

    if (t + 1 < NT) {
#pragma unroll
      for (int c = 0; c < 4; ++c) {
        GLL(gAn + (size_t)c * 16 * K, An + c * 4096 + wdst);
        GLL(gBn + (size_t)c * 16 * K, Bn + c * 4096 + wdst);
      }
      asm volatile("s_waitcnt vmcnt(8)" ::: "memory");
    } else {
      asm volatile("s_waitcnt vmcnt(0)" ::: "memory");
    }
    SBAR();

    bf16x8 a[4][2], b[4][2];
#pragma unroll
    for (int k = 0; k < 4; ++k)
#pragma unroll
      for (int i = 0; i < 2; ++i) {
        a[k][i] = *(const bf16x8*)(aRow + i * 4096 + colp[k]);
        b[k][i] = *(const bf16x8*)(bRow + i * 4096 + colp[k]);
      }
    WAIT_LGKM0();
    __builtin_amdgcn_s_setprio(1);
#pragma unroll
    for (int k = 0; k < 4; ++k)
#pragma unroll
      for (int i = 0; i < 2; ++i)
#pragma unroll
        for (int j = 0; j < 2; ++j)
          acc[i][j] = __builtin_amdgcn_mfma_f32_16x16x32_bf16(a[k][i], b[k][j], acc[i][j], 0, 0, 0);
    __builtin_amdgcn_s_setprio(0);
    SBAR();
  }

  // ---- epilogue: acc -> LDS (stride 68 floats kills bank conflicts) ----
  float* sacc = (float*)lds;   // [64][68], 17408 B, gemm bufs dead
  const int r0 = (lane >> 4) << 2;
  const int cc = lane & 15;
#pragma unroll
  for (int i = 0; i < 2; ++i)
#pragma unroll
    for (int j = 0; j < 2; ++j) {
      const int ml = wr * 32 + i * 16 + r0;
      const int nl = wc * 32 + j * 16 + cc;
#pragma unroll
      for (int r = 0; r < 4; ++r)
        sacc[(ml + r) * 68 + nl] = acc[i][j][r];
    }
  __syncthreads();

  // ---- cell: 64 batch x 16 j's; gates i,f,g,o = interleaved cols 4j+0..3
  for (int it = tid; it < 1024; it += 256) {
    const int bl = it >> 4;                 // local batch 0..63
    const int jl = it & 15;                 // local j 0..15
    const int b  = m0 + bl;
    const int jg = (n0 >> 2) + jl;          // global j
    const float4 hw = *(const float4*)&sacc[bl * 68 + jl * 4];
    const float4 xw = *(const float4*)&XW_f[(size_t)b * GATES + n0 + jl * 4];
    const float gi = xw.x + hw.x;
    const float gf = xw.y + hw.y;
    const float gg = xw.z + hw.z;
    const float go = xw.w + hw.w;
    const int cidx = b * HID + jg;
    const float cp = cbuf[cidx];
    const float cv = sigm(gf) * cp + sigm(gi) * tanhf(gg);
    const float h  = tanhf(sigm(go) * tanhf(cv));
    cbuf[cidx]    = cv;
    hbf_out[cidx] = f2bf(h);
    hs_f[cidx]    = h;
  }
}

// ---------------- first step: gates = XW' only (biases included) ----------------
__global__ void cell_first(const float* __restrict__ XW,
                           float* __restrict__ cbuf,
                           u16* __restrict__ hbf_out,
                           float* __restrict__ hs_f) {
  int it = blockIdx.x * blockDim.x + threadIdx.x;   // 256*1536 items
  int b = it / HID;
  int j = it - b * HID;
  const float4 xw = *(const float4*)&XW[(size_t)b * GATES + 4 * j];
  const float cv = sigm(xw.x) * tanhf(xw.z);
  const float h  = tanhf(sigm(xw.w) * tanhf(cv));
  cbuf[it]    = cv;
  hbf_out[it] = f2bf(h);
  hs_f[it]    = h;
}

// ---------------- final: out[b,n,o] = relu(out2[b,n,:]) @ lin_W^T + lin_b ----------------
__global__ __launch_bounds__(256) void final_k(const float* __restrict__ hs,
                                               const float* __restrict__ lin_W,
                                               const float* __restrict__ lin_b,
                                               float* __restrict__ out) {
  __shared__ float Wsh[12 * 36];
  __shared__ float bsh[12];
  for (int i = threadIdx.x; i < 12 * 36; i += blockDim.x) Wsh[i] = lin_W[i];
  if (threadIdx.x < 12) bsh[threadIdx.x] = lin_b[threadIdx.x];
  __syncthreads();

  int idx = blockIdx.x * blockDim.x + threadIdx.x;
  int b = idx >> 9;
  int n = idx & 511;

  float acc[12];
#pragma unroll
  for (int o = 0; o < 12; ++o) acc[o] = bsh[o];

#pragma unroll
  for (int kk = 0; kk < 3; ++kk)
#pragma unroll
    for (int f = 0; f < 12; ++f) {
      float v = hs[(size_t)(f * BSZ + b) * HID + 3 * n + kk];
      v = fmaxf(v, 0.0f);
      int j = 12 * kk + f;
#pragma unroll
      for (int o = 0; o < 12; ++o) acc[o] += v * Wsh[o * 36 + j];
    }

#pragma unroll
  for (int o = 0; o < 12; ++o) out[(size_t)idx * 12 + o] = acc[o];
}

extern "C" void kernel_launch(void* const* d_in, const int* in_sizes, int n_in,
                              void* d_out, int out_size, void* d_ws, size_t ws_size,
                              hipStream_t stream) {
  (void)in_sizes; (void)n_in; (void)out_size; (void)ws_size;
  const float* X     = (const float*)d_in[1];
  const float* W_ih  = (const float*)d_in[2];
  const float* W_hh  = (const float*)d_in[3];
  const float* b_ih  = (const float*)d_in[4];
  const float* b_hh  = (const float*)d_in[5];
  const float* lin_W = (const float*)d_in[6];
  const float* lin_b = (const float*)d_in[7];
  float* out = (float*)d_out;

  char* p = (char*)d_ws;
  u16*   Ax   = (u16*)p;   p += (size_t)MROWS * INSZ * 2;
  u16*   Wihb = (u16*)p;   p += (size_t)GATES * INSZ * 2;
  u16*   Whhb = (u16*)p;   p += (size_t)GATES * HID * 2;
  float* XW   = (float*)p; p += (size_t)MROWS * GATES * 4;
  u16*   hbfA = (u16*)p;   p += (size_t)BSZ * HID * 2;
  u16*   hbfB = (u16*)p;   p += (size_t)BSZ * HID * 2;
  float* cbuf = (float*)p; p += (size_t)BSZ * HID * 4;
  float* hs   = (float*)p; p += (size_t)FF * BSZ * HID * 4;

  hipFuncSetAttribute((const void*)gemm8p,
                      hipFuncAttributeMaxDynamicSharedMemorySize, LDS_TOTAL);

  // 1) convert weights (gate-interleaved rows) + pack X
  cvt_perm<<<(GATES * (INSZ / 4)) / 256, 256, 0, stream>>>(W_ih, Wihb, INSZ / 4);
  cvt_perm<<<(GATES * (HID / 4)) / 256, 256, 0, stream>>>(W_hh, Whhb, HID / 4);
  pack_x4<<<(BSZ * INSZ / 4) / 256, 256, 0, stream>>>(X, Ax);

  // 2) hoisted input GEMM: XW (interleaved cols) = Ax @ Wihb^T + biases
  gemm8p<<<256, 512, LDS_TOTAL, stream>>>(Ax, Wihb, b_ih, b_hh, XW,
                                          MROWS, GATES, INSZ);

  // 3) recurrence: fused GEMM+cell per step, hbf double-buffered
  u16* bufs[2] = { hbfA, hbfB };
  cell_first<<<(BSZ * HID) / 256, 256, 0, stream>>>(XW, cbuf, bufs[0], hs);
  for (int f = 1; f < FF; ++f) {
    gemm_cell<<<dim3(96, 4), 256, 0, stream>>>(
        bufs[(f - 1) & 1], Whhb, XW + (size_t)f * BSZ * GATES, cbuf,
        bufs[f & 1], hs + (size_t)f * BSZ * HID);
  }

  // 4) final linear
  final_k<<<(BSZ * NN) / 256, 256, 0, stream>>>(hs, lin_W, lin_b, out);
}

// Round 14
// 425.798 us; speedup vs baseline: 5.7408x; 1.0129x over previous
//
#include <hip/hip_runtime.h>
#include <hip/hip_bf16.h>
#include <stdint.h>

typedef uint16_t u16;
typedef __attribute__((ext_vector_type(8))) __bf16 bf16x8;
typedef __attribute__((ext_vector_type(4))) float f32x4;
typedef __attribute__((ext_vector_type(4))) u16 u16x4;

// Problem constants
#define BSZ   256
#define NN    512
#define TT    12
#define FF    12
#define HID   1536
#define INSZ  6144    // N*F = LSTM input size
#define GATES 6144    // 4*HID
#define MROWS 3072    // FF*BSZ rows of the hoisted input GEMM

static __device__ __forceinline__ u16 f2bf(float x) {
  uint32_t u = __builtin_bit_cast(uint32_t, x);
  u += 0x7fffu + ((u >> 16) & 1u);   // RNE
  return (u16)(u >> 16);
}

static __device__ __forceinline__ float sigm(float x) {
  return 1.0f / (1.0f + expf(-x));
}

// ---------------- fp32 -> bf16 convert + gate-interleave row permute ----------------
// out row' = 4*(r%HID) + r/HID  (orig row r = g*HID + j  ->  row' = 4j+g)
__global__ void cvt_perm(const float* __restrict__ in, u16* __restrict__ out,
                         int ncol4) {
  long idx = (long)blockIdx.x * blockDim.x + threadIdx.x;   // r*ncol4 + c4
  int r  = (int)(idx / ncol4);
  int c4 = (int)(idx - (long)r * ncol4);
  int rp = ((r % HID) << 2) + r / HID;
  float4 v = ((const float4*)in)[idx];
  u16x4 w = { f2bf(v.x), f2bf(v.y), f2bf(v.z), f2bf(v.w) };
  ((u16x4*)out)[(size_t)rp * ncol4 + c4] = w;
}

// ---------------- pack X: 4 k's per thread -> coalesced u16x4 writes ----------------
__global__ void pack_x4(const float* __restrict__ X, u16* __restrict__ Ax) {
  int idx = blockIdx.x * blockDim.x + threadIdx.x;   // (b, k4), k4 in [0,1536)
  int b  = idx / (INSZ / 4);
  int k4 = idx - b * (INSZ / 4);
  const float* xp = X + (size_t)b * (INSZ * FF) + (size_t)k4 * (4 * FF);
  float4 v[12];   // 48 floats = [kk 0..3][f 0..11]
#pragma unroll
  for (int j = 0; j < 12; ++j) v[j] = ((const float4*)xp)[j];
  const float* vf = (const float*)v;
#pragma unroll
  for (int f = 0; f < FF; ++f) {
    u16x4 w = { f2bf(vf[0 * FF + f]), f2bf(vf[1 * FF + f]),
                f2bf(vf[2 * FF + f]), f2bf(vf[3 * FF + f]) };
    *(u16x4*)&Ax[(size_t)(f * BSZ + b) * INSZ + k4 * 4] = w;
  }
}

// =====================================================================
// Deep-pipelined bf16 GEMM (R13: one-group-ahead read skew, 186 us,
// MfmaUtil 57%). Tile 192x384, BK=64, 8 waves, 2 barriers/K-tile.
// =====================================================================
#define BM8 192
#define BN8 384
#define LDSA_SZ 24576
#define LDSB_SZ 49152
#define LDS_TOTAL (2 * (LDSA_SZ + LDSB_SZ))   // 147456

#define GLL(src, dst)                                                          \
  __builtin_amdgcn_global_load_lds(                                            \
      (const __attribute__((address_space(1))) void*)(src),                    \
      (__attribute__((address_space(3))) void*)(dst), 16, 0, 0)

#define SBAR() asm volatile("s_barrier" ::: "memory")
#define SCHED_FENCE_DS() __builtin_amdgcn_sched_barrier(0x7F)
#define WAIT_LGKM0()                                                           \
  do {                                                                         \
    asm volatile("s_waitcnt lgkmcnt(0)" ::: "memory");                         \
    __builtin_amdgcn_sched_barrier(0);                                         \
  } while (0)

#define MFMA9(AF, BF, RO, CO)                                                  \
  do {                                                                         \
    __builtin_amdgcn_s_setprio(1);                                             \
    _Pragma("unroll") for (int i = 0; i < 3; ++i)                              \
        _Pragma("unroll") for (int j = 0; j < 3; ++j)                          \
            acc[RO + i][CO + j] = __builtin_amdgcn_mfma_f32_16x16x32_bf16(     \
                AF[i], BF[j], acc[RO + i][CO + j], 0, 0, 0);                   \
    __builtin_amdgcn_s_setprio(0);                                             \
  } while (0)

__global__ __launch_bounds__(512, 1) void gemm8p(
    const u16* __restrict__ A, const u16* __restrict__ Bt,
    const float* __restrict__ bi, const float* __restrict__ bh,
    float* __restrict__ C, int M, int N, int K) {
  extern __shared__ __align__(16) char lds[];
  const int tid  = threadIdx.x;
  const int lane = tid & 63;
  const int wid  = tid >> 6;
  const int wr   = wid >> 2;
  const int wc   = wid & 3;

  const int nbx  = N / BN8;
  const int cpx  = gridDim.x >> 3;
  const int orig = blockIdx.x;
  const int wgid = (orig & 7) * cpx + (orig >> 3);
  const int m0   = (wgid / nbx) * BM8;
  const int n0   = (wgid % nbx) * BN8;

  const int fr    = lane & 15;
  const int kb    = (lane >> 4) << 4;
  const int swz   = (fr & 7) << 4;
  const int colp0 = kb ^ swz;
  const int colp1 = (64 | kb) ^ swz;

  const int srow = tid >> 3;
  const int scb  = ((tid & 7) << 4) ^ ((srow & 7) << 4);
  const u16* gA = A  + (size_t)(m0 + srow) * K + (scb >> 1);
  const u16* gB = Bt + (size_t)(n0 + srow) * K + (scb >> 1);
  const int wdst = wid << 10;

  char* ldsA = lds;
  char* ldsB = lds + 2 * LDSA_SZ;
  char* aRowB = ldsA + (wr * 96 + fr) * 128;
  char* bRowB = ldsB + (wc * 96 + fr) * 128;

  f32x4 acc[6][6] = {};
  const int NT = K >> 6;

#pragma unroll
  for (int c = 0; c < 3; ++c) GLL(gA + (size_t)c * 64 * K, ldsA + c * 8192 + wdst);
#pragma unroll
  for (int c = 0; c < 6; ++c) GLL(gB + (size_t)c * 64 * K, ldsB + c * 8192 + wdst);

  for (int t = 0; t < NT; ++t) {
    const int p = t & 1;
    char* aRow = aRowB + p * LDSA_SZ;
    char* bRow = bRowB + p * LDSB_SZ;
    char* An = ldsA + (p ^ 1) * LDSA_SZ;
    char* Bn = ldsB + (p ^ 1) * LDSB_SZ;
    const u16* gAn = gA + (size_t)(t + 1) * 64;
    const u16* gBn = gB + (size_t)(t + 1) * 64;
    const bool pf = (t + 1 < NT);

    bf16x8 a0[2][3], a1[2][3], b0[2][3], b1[2][3];

    if (pf) {
#pragma unroll
      for (int c = 0; c < 3; ++c) GLL(gAn + (size_t)c * 64 * K, An + c * 8192 + wdst);
      asm volatile("s_waitcnt vmcnt(3)" ::: "memory");
    } else {
      asm volatile("s_waitcnt vmcnt(0)" ::: "memory");
    }
    SBAR();

    // ---- p0: read a0k0 + b0k0
#pragma unroll
    for (int i = 0; i < 3; ++i) {
      a0[0][i] = *(const bf16x8*)(aRow + i * 2048 + colp0);
      b0[0][i] = *(const bf16x8*)(bRow + i * 2048 + colp0);
    }
    // ---- p1: read b1k0 ; q00k0
#pragma unroll
    for (int i = 0; i < 3; ++i) b1[0][i] = *(const bf16x8*)(bRow + (3 + i) * 2048 + colp0);
    MFMA9(a0[0], b0[0], 0, 0);
    if (pf) {
      GLL(gBn + (size_t)0 * 64 * K, Bn + 0 * 8192 + wdst);
      GLL(gBn + (size_t)1 * 64 * K, Bn + 1 * 8192 + wdst);
    }
    SCHED_FENCE_DS();

    // ---- p2: read a1k0 ; q01k0
#pragma unroll
    for (int i = 0; i < 3; ++i) a1[0][i] = *(const bf16x8*)(aRow + (3 + i) * 2048 + colp0);
    MFMA9(a0[0], b1[0], 0, 3);
    if (pf) {
      GLL(gBn + (size_t)2 * 64 * K, Bn + 2 * 8192 + wdst);
      GLL(gBn + (size_t)3 * 64 * K, Bn + 3 * 8192 + wdst);
    }
    SCHED_FENCE_DS();

    // ---- p3: read a0k1 ; q11k0
#pragma unroll
    for (int i = 0; i < 3; ++i) a0[1][i] = *(const bf16x8*)(aRow + i * 2048 + colp1);
    MFMA9(a1[0], b1[0], 3, 3);
    if (pf) {
      GLL(gBn + (size_t)4 * 64 * K, Bn + 4 * 8192 + wdst);
      GLL(gBn + (size_t)5 * 64 * K, Bn + 5 * 8192 + wdst);
    }
    SCHED_FENCE_DS();

    // ---- p4: read b0k1 ; q10k0
#pragma unroll
    for (int i = 0; i < 3; ++i) b0[1][i] = *(const bf16x8*)(bRow + i * 2048 + colp1);
    MFMA9(a1[0], b0[0], 3, 0);
    SCHED_FENCE_DS();

    // ---- p5: read b1k1 ; q00k1
#pragma unroll
    for (int i = 0; i < 3; ++i) b1[1][i] = *(const bf16x8*)(bRow + (3 + i) * 2048 + colp1);
    MFMA9(a0[1], b0[1], 0, 0);
    SCHED_FENCE_DS();

    // ---- p6: read a1k1 ; q01k1
#pragma unroll
    for (int i = 0; i < 3; ++i) a1[1][i] = *(const bf16x8*)(aRow + (3 + i) * 2048 + colp1);
    MFMA9(a0[1], b1[1], 0, 3);
    SCHED_FENCE_DS();

    // ---- p7: q11k1 ; q10k1
    MFMA9(a1[1], b1[1], 3, 3);
    MFMA9(a1[1], b0[1], 3, 0);

    SBAR();
  }

  const int r0 = (lane >> 4) << 2;
  const int cc = lane & 15;
#pragma unroll
  for (int j = 0; j < 6; ++j) {
    const int col = n0 + wc * 96 + j * 16 + cc;          // interleaved position
    const int oc  = (col & 3) * HID + (col >> 2);        // original gate index
    const float bv = bi[oc] + bh[oc];
#pragma unroll
    for (int i = 0; i < 6; ++i) {
      const size_t rbase = (size_t)(m0 + wr * 96 + i * 16 + r0) * N + col;
#pragma unroll
      for (int r = 0; r < 4; ++r)
        C[rbase + (size_t)r * N] = acc[i][j][r] + bv;
    }
  }
}

// =====================================================================
// Fused step (R14: back to BK=64/32KB — R12's known-good config — plus
// XCD-aware block mapping: XCD x = orig&7 owns n-tiles [12x,12x+12) x all
// 4 m-tiles, so each 197KB Whhb panel is read once per XCD (2.4MB/XCD
// working set fits 4MB L2, 4x reuse) instead of refetched per m-tile.
// Grid flat 384. Gate-interleaved layout -> cell in epilogue.
// =====================================================================
__global__ __launch_bounds__(256, 4) void gemm_cell(
    const u16* __restrict__ hbf_in,    // (256 x 1536) bf16 h(t-1)
    const u16* __restrict__ Whhb,      // (6144 x 1536) bf16, rows interleaved
    const float* __restrict__ XW_f,    // (256 x 6144) interleaved, biases in
    float* __restrict__ cbuf,          // (256 x 1536) c state (in-place)
    u16* __restrict__ hbf_out,         // (256 x 1536) bf16 h(t)
    float* __restrict__ hs_f) {        // (256 x 1536) fp32 h(t) slice
  __shared__ __align__(16) char lds[32768];
  const int tid  = threadIdx.x;
  const int lane = tid & 63;
  const int wid  = tid >> 6;
  const int wr   = wid >> 1;   // 0..1
  const int wc   = wid & 1;    // 0..1

  // XCD-aware mapping (bijective): x = orig&7 (HW round-robin XCD id),
  // j = orig>>3; n-tile = 12x + j/4, m-tile = j%4.
  const int orig = blockIdx.x;
  const int xcd  = orig & 7;
  const int jj   = orig >> 3;
  const int n0   = (12 * xcd + (jj >> 2)) * 64;   // interleaved col base
  const int m0   = (jj & 3) * 64;                 // batch base
  const int K    = HID;

  const int fr    = lane & 15;
  const int kb    = (lane >> 4) << 4;
  const int swz   = (fr & 7) << 4;
  const int colp0 = kb ^ swz;
  const int colp1 = (64 | kb) ^ swz;

  const int srow = tid >> 3;
  const int scb  = ((tid & 7) << 4) ^ ((srow & 7) << 4);
  const u16* gA = hbf_in + (size_t)(m0 + srow) * K + (scb >> 1);
  const u16* gB = Whhb   + (size_t)(n0 + srow) * K + (scb >> 1);
  const int wdst = wid << 10;

  char* ldsA = lds;            // [2][8192]
  char* ldsB = lds + 16384;    // [2][8192]
  char* aRowB = ldsA + (wr * 32 + fr) * 128;
  char* bRowB = ldsB + (wc * 32 + fr) * 128;

  f32x4 acc[2][2] = {};
  const int NT = K >> 6;   // 24

  GLL(gA,                  ldsA + wdst);
  GLL(gA + (size_t)32 * K, ldsA + 4096 + wdst);
  GLL(gB,                  ldsB + wdst);
  GLL(gB + (size_t)32 * K, ldsB + 4096 + wdst);

  for (int t = 0; t < NT; ++t) {
    const int p = t & 1;
    char* aRow = aRowB + p * 8192;
    char* bRow = bRowB + p * 8192;
    char* An = ldsA + (p ^ 1) * 8192;
    char* Bn = ldsB + (p ^ 1) * 8192;
    const u16* gAn = gA + (size_t)(t + 1) * 64;
    const u16* gBn = gB + (size_t)(t + 1) * 64;

    if (t + 1 < NT) {
      GLL(gAn,                  An + wdst);
      GLL(gAn + (size_t)32 * K, An + 4096 + wdst);
      GLL(gBn,                  Bn + wdst);
      GLL(gBn + (size_t)32 * K, Bn + 4096 + wdst);
      asm volatile("s_waitcnt vmcnt(4)" ::: "memory");
    } else {
      asm volatile("s_waitcnt vmcnt(0)" ::: "memory");
    }
    SBAR();

    bf16x8 a[2][2], b[2][2];
#pragma unroll
    for (int i = 0; i < 2; ++i) {
      a[0][i] = *(const bf16x8*)(aRow + i * 2048 + colp0);
      a[1][i] = *(const bf16x8*)(aRow + i * 2048 + colp1);
      b[0][i] = *(const bf16x8*)(bRow + i * 2048 + colp0);
      b[1][i] = *(const bf16x8*)(bRow + i * 2048 + colp1);
    }
    WAIT_LGKM0();
    __builtin_amdgcn_s_setprio(1);
#pragma unroll
    for (int i = 0; i < 2; ++i)
#pragma unroll
      for (int j = 0; j < 2; ++j) {
        acc[i][j] = __builtin_amdgcn_mfma_f32_16x16x32_bf16(a[0][i], b[0][j], acc[i][j], 0, 0, 0);
        acc[i][j] = __builtin_amdgcn_mfma_f32_16x16x32_bf16(a[1][i], b[1][j], acc[i][j], 0, 0, 0);
      }
    __builtin_amdgcn_s_setprio(0);
    SBAR();
  }

  // ---- epilogue: acc -> LDS (stride 68 floats kills bank conflicts) ----
  float* sacc = (float*)lds;   // [64][68], 17408 B, gemm bufs dead
  const int r0 = (lane >> 4) << 2;
  const int cc = lane & 15;
#pragma unroll
  for (int i = 0; i < 2; ++i)
#pragma unroll
    for (int j = 0; j < 2; ++j) {
      const int ml = wr * 32 + i * 16 + r0;
      const int nl = wc * 32 + j * 16 + cc;
#pragma unroll
      for (int r = 0; r < 4; ++r)
        sacc[(ml + r) * 68 + nl] = acc[i][j][r];
    }
  __syncthreads();

  // ---- cell: 64 batch x 16 j's; gates i,f,g,o = interleaved cols 4j+0..3
  for (int it = tid; it < 1024; it += 256) {
    const int bl = it >> 4;                 // local batch 0..63
    const int jl = it & 15;                 // local j 0..15
    const int b  = m0 + bl;
    const int jg = (n0 >> 2) + jl;          // global j
    const float4 hw = *(const float4*)&sacc[bl * 68 + jl * 4];
    const float4 xw = *(const float4*)&XW_f[(size_t)b * GATES + n0 + jl * 4];
    const float gi = xw.x + hw.x;
    const float gf = xw.y + hw.y;
    const float gg = xw.z + hw.z;
    const float go = xw.w + hw.w;
    const int cidx = b * HID + jg;
    const float cp = cbuf[cidx];
    const float cv = sigm(gf) * cp + sigm(gi) * tanhf(gg);
    const float h  = tanhf(sigm(go) * tanhf(cv));
    cbuf[cidx]    = cv;
    hbf_out[cidx] = f2bf(h);
    hs_f[cidx]    = h;
  }
}

// ---------------- first step: gates = XW' only (biases included) ----------------
__global__ void cell_first(const float* __restrict__ XW,
                           float* __restrict__ cbuf,
                           u16* __restrict__ hbf_out,
                           float* __restrict__ hs_f) {
  int it = blockIdx.x * blockDim.x + threadIdx.x;   // 256*1536 items
  int b = it / HID;
  int j = it - b * HID;
  const float4 xw = *(const float4*)&XW[(size_t)b * GATES + 4 * j];
  const float cv = sigm(xw.x) * tanhf(xw.z);
  const float h  = tanhf(sigm(xw.w) * tanhf(cv));
  cbuf[it]    = cv;
  hbf_out[it] = f2bf(h);
  hs_f[it]    = h;
}

// ---------------- final: out[b,n,o] = relu(out2[b,n,:]) @ lin_W^T + lin_b ----------------
__global__ __launch_bounds__(256) void final_k(const float* __restrict__ hs,
                                               const float* __restrict__ lin_W,
                                               const float* __restrict__ lin_b,
                                               float* __restrict__ out) {
  __shared__ float Wsh[12 * 36];
  __shared__ float bsh[12];
  for (int i = threadIdx.x; i < 12 * 36; i += blockDim.x) Wsh[i] = lin_W[i];
  if (threadIdx.x < 12) bsh[threadIdx.x] = lin_b[threadIdx.x];
  __syncthreads();

  int idx = blockIdx.x * blockDim.x + threadIdx.x;
  int b = idx >> 9;
  int n = idx & 511;

  float acc[12];
#pragma unroll
  for (int o = 0; o < 12; ++o) acc[o] = bsh[o];

#pragma unroll
  for (int kk = 0; kk < 3; ++kk)
#pragma unroll
    for (int f = 0; f < 12; ++f) {
      float v = hs[(size_t)(f * BSZ + b) * HID + 3 * n + kk];
      v = fmaxf(v, 0.0f);
      int j = 12 * kk + f;
#pragma unroll
      for (int o = 0; o < 12; ++o) acc[o] += v * Wsh[o * 36 + j];
    }

#pragma unroll
  for (int o = 0; o < 12; ++o) out[(size_t)idx * 12 + o] = acc[o];
}

extern "C" void kernel_launch(void* const* d_in, const int* in_sizes, int n_in,
                              void* d_out, int out_size, void* d_ws, size_t ws_size,
                              hipStream_t stream) {
  (void)in_sizes; (void)n_in; (void)out_size; (void)ws_size;
  const float* X     = (const float*)d_in[1];
  const float* W_ih  = (const float*)d_in[2];
  const float* W_hh  = (const float*)d_in[3];
  const float* b_ih  = (const float*)d_in[4];
  const float* b_hh  = (const float*)d_in[5];
  const float* lin_W = (const float*)d_in[6];
  const float* lin_b = (const float*)d_in[7];
  float* out = (float*)d_out;

  char* p = (char*)d_ws;
  u16*   Ax   = (u16*)p;   p += (size_t)MROWS * INSZ * 2;
  u16*   Wihb = (u16*)p;   p += (size_t)GATES * INSZ * 2;
  u16*   Whhb = (u16*)p;   p += (size_t)GATES * HID * 2;
  float* XW   = (float*)p; p += (size_t)MROWS * GATES * 4;
  u16*   hbfA = (u16*)p;   p += (size_t)BSZ * HID * 2;
  u16*   hbfB = (u16*)p;   p += (size_t)BSZ * HID * 2;
  float* cbuf = (float*)p; p += (size_t)BSZ * HID * 4;
  float* hs   = (float*)p; p += (size_t)FF * BSZ * HID * 4;

  hipFuncSetAttribute((const void*)gemm8p,
                      hipFuncAttributeMaxDynamicSharedMemorySize, LDS_TOTAL);

  // 1) convert weights (gate-interleaved rows) + pack X
  cvt_perm<<<(GATES * (INSZ / 4)) / 256, 256, 0, stream>>>(W_ih, Wihb, INSZ / 4);
  cvt_perm<<<(GATES * (HID / 4)) / 256, 256, 0, stream>>>(W_hh, Whhb, HID / 4);
  pack_x4<<<(BSZ * INSZ / 4) / 256, 256, 0, stream>>>(X, Ax);

  // 2) hoisted input GEMM: XW (interleaved cols) = Ax @ Wihb^T + biases
  gemm8p<<<256, 512, LDS_TOTAL, stream>>>(Ax, Wihb, b_ih, b_hh, XW,
                                          MROWS, GATES, INSZ);

  // 3) recurrence: fused GEMM+cell per step, hbf double-buffered
  u16* bufs[2] = { hbfA, hbfB };
  cell_first<<<(BSZ * HID) / 256, 256, 0, stream>>>(XW, cbuf, bufs[0], hs);
  for (int f = 1; f < FF; ++f) {
    gemm_cell<<<384, 256, 0, stream>>>(
        bufs[(f - 1) & 1], Whhb, XW + (size_t)f * BSZ * GATES, cbuf,
        bufs[f & 1], hs + (size_t)f * BSZ * HID);
  }

  // 4) final linear
  final_k<<<(BSZ * NN) / 256, 256, 0, stream>>>(hs, lin_W, lin_b, out);
}